// Round 8
// baseline (79584.369 us; speedup 1.0000x reference)
//
#include <hip/hip_runtime.h>

#define HH 128      // hidden size
#define G4 512      // 4*HH gates
#define TT 102400   // sequence length
#define BB 8        // batch
#define HS 144      // LDS h stride per batch (halfs): 128 + 16 pad, 16B-aligned
#define HBUFH (BB * HS)   // 1152 halfs per buffer

typedef _Float16 v2h __attribute__((ext_vector_type(2)));
typedef _Float16 v8h __attribute__((ext_vector_type(8)));
typedef float f32x4 __attribute__((ext_vector_type(4)));

#define MFMA16(a, b, c) __builtin_amdgcn_mfma_f32_16x16x32_f16((a), (b), (c), 0, 0, 0)

#if __has_builtin(__builtin_amdgcn_fdot2)
#define FDOT2(a, b, c) __builtin_amdgcn_fdot2((a), (b), (c), false)
#else
static __device__ __forceinline__ float fdot2_fb(v2h a, v2h b, float c) {
    return fmaf((float)a[0], (float)b[0], fmaf((float)a[1], (float)b[1], c));
}
#define FDOT2(a, b, c) fdot2_fb((a), (b), (c))
#endif

template<int CTRL>
__device__ __forceinline__ float dpp_mov(float v) {
    return __int_as_float(
        __builtin_amdgcn_update_dpp(0, __float_as_int(v), CTRL, 0xF, 0xF, true));
}

__device__ __forceinline__ float sig_f(float x) {
    return __builtin_amdgcn_rcpf(1.0f + __expf(-x));
}
__device__ __forceinline__ float tanh_f(float x) {
    return fmaf(2.0f, __builtin_amdgcn_rcpf(1.0f + __expf(-2.0f * x)), -1.0f);
}

union HI { int i; v2h h; };

// ---------------- stage-B helpers (R7, verified) ---------------------------
__device__ __forceinline__ float dotred(const v2h w[8][8],
                                        const _Float16* __restrict__ hsl,
                                        bool bp1, bool bp2, bool bp3) {
    const int4* hp4 = (const int4*)hsl;
    int4 ha = hp4[0], hb = hp4[1];
    int hp[8] = {ha.x, ha.y, ha.z, ha.w, hb.x, hb.y, hb.z, hb.w};
    float acc[8];
#pragma unroll
    for (int r = 0; r < 8; ++r) acc[r] = 0.f;
#pragma unroll
    for (int i = 0; i < 8; ++i) {
        HI u; u.i = hp[i];
#pragma unroll
        for (int r = 0; r < 8; ++r) acc[r] = FDOT2(w[r][i], u.h, acc[r]);
    }
    float b0[4];
#pragma unroll
    for (int m = 0; m < 4; ++m) {
        float send = bp1 ? acc[2 * m] : acc[2 * m + 1];
        float keep = bp1 ? acc[2 * m + 1] : acc[2 * m];
        b0[m] = keep + dpp_mov<0xB1>(send);
    }
    float d0[2];
#pragma unroll
    for (int i = 0; i < 2; ++i) {
        float send = bp2 ? b0[i] : b0[i + 2];
        float keep = bp2 ? b0[i + 2] : b0[i];
        d0[i] = keep + dpp_mov<0x4E>(send);
    }
    float send = bp3 ? d0[0] : d0[1];
    float keep = bp3 ? d0[1] : d0[0];
    return keep + dpp_mov<0x141>(send);
}

__device__ __forceinline__ void load_w8h(const float* __restrict__ W,
                                         int Q, int j, v2h w[8][8]) {
#pragma unroll
    for (int r = 0; r < 8; ++r) {
        int row = 2 * Q + (r & 1) + 128 * (r >> 1);
        const float4* rp = (const float4*)(W + (size_t)row * HH + 16 * j);
#pragma unroll
        for (int i = 0; i < 4; ++i) {
            float4 f = rp[i];
            w[r][2 * i]     = (v2h){(_Float16)f.x, (_Float16)f.y};
            w[r][2 * i + 1] = (v2h){(_Float16)f.z, (_Float16)f.w};
        }
    }
}

// ---------------------------------------------------------------------------
// One pipeline slot (512 threads/block):
//   block 0      = stage A (layer0 chain, chunk c, ALL 8 batches, MFMA)
//   block 1      = stage C (layer1 chain, chunk c-2, ALL 8 batches, MFMA)
//   blocks 2..65 = stage B (xp1 GEMM, chunk c-1): 8 batch x 8 t-slice (R7 VALU)
// MFMA layouts (m89/m120-verified): A[m=lane&15][k=quad*8+j],
// B[k=quad*8+j][n=lane&15], D[m=quad*4+r][n=lane&15].
// B cols clamped to n&7 -> cols 8-15 duplicate 0-7; every lane owns
// (batch=lane&7, cells myc0..myc0+1) with all 4 gates local. No gathers.
// ---------------------------------------------------------------------------
__global__ void __launch_bounds__(512, 2)
lstm_slot_kernel(
    const float* __restrict__ x,
    const float* __restrict__ Wih0, const float* __restrict__ Whh0,
    const float* __restrict__ bih0, const float* __restrict__ bhh0,
    const float* __restrict__ Wih1, const float* __restrict__ Whh1,
    const float* __restrict__ bih1, const float* __restrict__ bhh1,
    float* __restrict__ h1s, float* __restrict__ c1s,
    float* __restrict__ h2s, float* __restrict__ c2s,
    double* __restrict__ pooled,
    _Float16* __restrict__ h1ring,  // [2][B][chunkT][HH] fp16
    float* __restrict__ xpring,     // [2][B][chunkT][HH][4] (t,cell,gate) f32
    int c, int chunkT, int nchunks)
{
    __shared__ __align__(16) _Float16 hsh[2 * HBUFH];   // 4608 B
    const int t = threadIdx.x;

    if (blockIdx.x < 2) {
        // =============== MFMA chain stages (A: layer0, C: layer1) ==========
        const bool isA = (blockIdx.x == 0);
        const int cc = isA ? c : (c - 2);
        if (cc < 0 || cc >= nchunks) return;
        const int lane = t & 63, wv = t >> 6;
        const int quad = lane >> 4, n16 = lane & 15, nb = lane & 7;
        const int hi = (lane >> 3) & 1;
        const int mrow0 = 16 * wv;                 // wave's cell-block base
        const int myc0 = mrow0 + quad * 4 + 2 * hi; // my 2 cells: myc0, myc0+1

        // ---- A-frags: weights fp32 -> fp16 registers (once per slot) ----
        v8h a[4][4];
        const float* Wl = isA ? Whh0 : Whh1;
#pragma unroll
        for (int g = 0; g < 4; ++g)
#pragma unroll
            for (int kt = 0; kt < 4; ++kt) {
                const float* rp = Wl + (size_t)(mrow0 + n16 + 128 * g) * HH
                                + 32 * kt + quad * 8;
                v8h av;
#pragma unroll
                for (int e = 0; e < 8; ++e) av[e] = (_Float16)rp[e];
                a[g][kt] = av;
            }
        // bias folded into MFMA C-init (layer1 bias already in xp via stage B)
        f32x4 biasf[4];
#pragma unroll
        for (int g = 0; g < 4; ++g) {
            f32x4 bv = {0.f, 0.f, 0.f, 0.f};
            if (isA) {
#pragma unroll
                for (int r = 0; r < 4; ++r) {
                    int row = mrow0 + quad * 4 + r + 128 * g;
                    bv[r] = bih0[row] + bhh0[row];
                }
            }
            biasf[g] = bv;
        }
        float wih2[4][2];
        if (isA) {
#pragma unroll
            for (int g = 0; g < 4; ++g)
#pragma unroll
                for (int e = 0; e < 2; ++e)
                    wih2[g][e] = Wih0[myc0 + e + 128 * g];
        }
        float* cst = isA ? c1s : c2s;
        float* hst = isA ? h1s : h2s;
        float cr0 = cst[nb * HH + myc0], cr1 = cst[nb * HH + myc0 + 1];
        hsh[nb * HS + myc0]     = (_Float16)hst[nb * HH + myc0];
        hsh[nb * HS + myc0 + 1] = (_Float16)hst[nb * HH + myc0 + 1];

        _Float16* ringp = h1ring + ((size_t)((c & 1) * BB + nb)) * (size_t)chunkT * HH;
        const float* xps = xpring
            + ((size_t)((cc & 1) * BB + nb)) * (size_t)chunkT * G4 + 4 * myc0;
        const float4* xb4 = (const float4*)(x + (size_t)nb * TT + (size_t)cc * chunkT);
        const int nt4 = chunkT >> 2;

        float4 xcur = {0, 0, 0, 0}, xnxt = {0, 0, 0, 0};
        float4 xpc[4][2], xpn[4][2];
        if (isA) {
            xcur = xb4[0];
        } else {
#pragma unroll
            for (int u = 0; u < 4; ++u) {
                const float4* p = (const float4*)(xps + (size_t)u * G4);
                xpc[u][0] = p[0]; xpc[u][1] = p[1];
            }
        }
        float h0 = 0.f, h1 = 0.f;
        double pa0 = 0.0, pa1 = 0.0;
        __syncthreads();

        for (int t4 = 0; t4 < nt4; ++t4) {
            if (isA) xnxt = (t4 + 1 < nt4) ? xb4[t4 + 1] : xcur;
#pragma unroll
            for (int u = 0; u < 4; ++u) {
                const int buf = u & 1;
                if (!isA) {      // prefetch xp 4 steps ahead (HBM latency)
                    int pg = (t4 + 1 < nt4) ? (t4 + 1) : t4;
                    const float4* p = (const float4*)(xps + (size_t)(pg * 4 + u) * G4);
                    xpn[u][0] = p[0]; xpn[u][1] = p[1];
                }
                // B-frags (shared across the wave's 16 MFMAs)
                const _Float16* hb = hsh + buf * HBUFH + nb * HS + 8 * quad;
                v8h bf0 = *(const v8h*)(hb);
                v8h bf1 = *(const v8h*)(hb + 32);
                v8h bf2 = *(const v8h*)(hb + 64);
                v8h bf3 = *(const v8h*)(hb + 96);
                f32x4 d0 = biasf[0], d1 = biasf[1], d2 = biasf[2], d3 = biasf[3];
                d0 = MFMA16(a[0][0], bf0, d0); d1 = MFMA16(a[1][0], bf0, d1);
                d2 = MFMA16(a[2][0], bf0, d2); d3 = MFMA16(a[3][0], bf0, d3);
                d0 = MFMA16(a[0][1], bf1, d0); d1 = MFMA16(a[1][1], bf1, d1);
                d2 = MFMA16(a[2][1], bf1, d2); d3 = MFMA16(a[3][1], bf1, d3);
                d0 = MFMA16(a[0][2], bf2, d0); d1 = MFMA16(a[1][2], bf2, d1);
                d2 = MFMA16(a[2][2], bf2, d2); d3 = MFMA16(a[3][2], bf2, d3);
                d0 = MFMA16(a[0][3], bf3, d0); d1 = MFMA16(a[1][3], bf3, d1);
                d2 = MFMA16(a[2][3], bf3, d2); d3 = MFMA16(a[3][3], bf3, d3);
                // my 2 cells' pre-activations (rows 2*hi, 2*hi+1)
                float p00 = hi ? d0[2] : d0[0], p01 = hi ? d0[3] : d0[1];
                float p10 = hi ? d1[2] : d1[0], p11 = hi ? d1[3] : d1[1];
                float p20 = hi ? d2[2] : d2[0], p21 = hi ? d2[3] : d2[1];
                float p30 = hi ? d3[2] : d3[0], p31 = hi ? d3[3] : d3[1];
                if (isA) {
                    float xt = (u == 0) ? xcur.x : (u == 1) ? xcur.y
                             : (u == 2) ? xcur.z : xcur.w;
                    p00 = fmaf(xt, wih2[0][0], p00); p01 = fmaf(xt, wih2[0][1], p01);
                    p10 = fmaf(xt, wih2[1][0], p10); p11 = fmaf(xt, wih2[1][1], p11);
                    p20 = fmaf(xt, wih2[2][0], p20); p21 = fmaf(xt, wih2[2][1], p21);
                    p30 = fmaf(xt, wih2[3][0], p30); p31 = fmaf(xt, wih2[3][1], p31);
                } else {
                    p00 += xpc[u][0].x; p10 += xpc[u][0].y;
                    p20 += xpc[u][0].z; p30 += xpc[u][0].w;
                    p01 += xpc[u][1].x; p11 += xpc[u][1].y;
                    p21 += xpc[u][1].z; p31 += xpc[u][1].w;
                }
                float i0 = sig_f(p00), f0 = sig_f(p10);
                float g0 = tanh_f(p20), o0 = sig_f(p30);
                float i1 = sig_f(p01), f1 = sig_f(p11);
                float g1 = tanh_f(p21), o1 = sig_f(p31);
                cr0 = fmaf(f0, cr0, i0 * g0);
                cr1 = fmaf(f1, cr1, i1 * g1);
                h0 = o0 * tanh_f(cr0);
                h1 = o1 * tanh_f(cr1);
                v2h hp; hp[0] = (_Float16)h0; hp[1] = (_Float16)h1;   // RNE
                *(v2h*)(hsh + (buf ^ 1) * HBUFH + nb * HS + myc0) = hp;
                if (isA) {
                    *(v2h*)(ringp + (size_t)(t4 * 4 + u) * HH + myc0) = hp;
                } else {
                    pa0 += (double)h0; pa1 += (double)h1;
                }
                __syncthreads();
            }
            xcur = xnxt;
            if (!isA) {
#pragma unroll
                for (int u = 0; u < 4; ++u) {
                    xpc[u][0] = xpn[u][0]; xpc[u][1] = xpn[u][1];
                }
            }
        }
        cst[nb * HH + myc0]     = cr0;
        cst[nb * HH + myc0 + 1] = cr1;
        hst[nb * HH + myc0]     = h0;
        hst[nb * HH + myc0 + 1] = h1;
        if (!isA) {
            pooled[nb * HH + myc0]     += pa0;
            pooled[nb * HH + myc0 + 1] += pa1;
        }

    } else {
        // ---------------- stage B: xp1 = Wih1 @ h1 + bias, chunk c-1 -------
        const int bc = c - 1;
        if (bc < 0 || bc >= nchunks) return;
        const int ib = blockIdx.x - 2;        // 0..63
        const int bb = ib >> 3;               // batch
        const int sl = ib & 7;                // t-slice (stride 8)
        const int Q = t >> 3, j = t & 7;
        const bool bp1 = ((j ^ (j >> 2)) & 1) != 0;
        const bool bp2 = ((j ^ (j >> 1)) & 1) != 0;
        const bool bp3 = ((j >> 2) & 1) != 0;
        const int cellj = bp1 ? 1 : 0;
        const int gatej = (bp2 ? 2 : 0) + (bp3 ? 1 : 0);
        const int myc = 2 * Q + cellj;
        const int myrow = myc + 128 * gatej;
        v2h w[8][8];
        load_w8h(Wih1, Q, j, w);
        const float bias_l = bih1[myrow] + bhh1[myrow];
        const _Float16* hrp = h1ring
            + ((size_t)((bc & 1) * BB + bb)) * (size_t)chunkT * HH;
        float* xpw = xpring + ((size_t)((bc & 1) * BB + bb)) * (size_t)chunkT * G4;
        if (t < HH) hsh[t] = hrp[(size_t)sl * HH + t];
        __syncthreads();
        int pb = 0;
        for (int tt = sl; tt < chunkT; tt += 8) {
            int ttn = tt + 8;
            bool pf = (t < HH) && (ttn < chunkT);
            _Float16 hn = (_Float16)0.f;
            if (pf) hn = hrp[(size_t)ttn * HH + t];
            float sfin = dotred(w, hsh + pb * HH + 16 * j, bp1, bp2, bp3);
            if (pf) hsh[(pb ^ 1) * HH + t] = hn;
            xpw[(size_t)tt * G4 + 4 * myc + gatej] = sfin + bias_l;
            __syncthreads();
            pb ^= 1;
        }
    }
}

// ---------------- head: mean-pool (done) -> FC+ReLU -> FC ------------------
__global__ void head_kernel(const double* __restrict__ pooled,
                            const float* __restrict__ fcW1, const float* __restrict__ fcb1,
                            const float* __restrict__ fcW2, const float* __restrict__ fcb2,
                            float* __restrict__ out)
{
    __shared__ float p_s[HH];
    __shared__ float hid_s[64];
    const int b = blockIdx.x, t = threadIdx.x;
    if (t < HH) p_s[t] = (float)(pooled[b * HH + t] * (1.0 / (double)TT));
    __syncthreads();
    if (t < 64) {
        float acc = fcb1[t];
#pragma unroll 8
        for (int k = 0; k < HH; ++k) acc = fmaf(p_s[k], fcW1[t * HH + k], acc);
        hid_s[t] = fmaxf(acc, 0.f);
    }
    __syncthreads();
    if (t < 11) {
        float acc = fcb2[t];
#pragma unroll
        for (int k = 0; k < 64; ++k) acc = fmaf(hid_s[k], fcW2[t * 64 + k], acc);
        out[b * 11 + t] = acc;
    }
}

// ---------------------------------------------------------------------------
extern "C" void kernel_launch(void* const* d_in, const int* in_sizes, int n_in,
                              void* d_out, int out_size, void* d_ws, size_t ws_size,
                              hipStream_t stream)
{
    const float* x    = (const float*)d_in[0];
    const float* Wih0 = (const float*)d_in[1];
    const float* Whh0 = (const float*)d_in[2];
    const float* bih0 = (const float*)d_in[3];
    const float* bhh0 = (const float*)d_in[4];
    const float* Wih1 = (const float*)d_in[5];
    const float* Whh1 = (const float*)d_in[6];
    const float* bih1 = (const float*)d_in[7];
    const float* bhh1 = (const float*)d_in[8];
    const float* fcW1 = (const float*)d_in[9];
    const float* fcb1 = (const float*)d_in[10];
    const float* fcW2 = (const float*)d_in[11];
    const float* fcb2 = (const float*)d_in[12];
    float* out = (float*)d_out;

    // ---- workspace layout ----
    char* wsp = (char*)d_ws;
    float*  h1s    = (float*) (wsp + 0);
    float*  c1s    = (float*) (wsp + 4096);
    float*  h2s    = (float*) (wsp + 8192);
    float*  c2s    = (float*) (wsp + 12288);
    double* pooled = (double*)(wsp + 16384);          // 8 KB
    const size_t STATE_BYTES = 24576;

    // per-t ring bytes: h1 fp16 2*8*128*2 = 4096 ; xp fp32 2*8*512*4 = 32768
    static const int cands[] = {3200, 1600, 800, 400, 160, 80, 40, 8};
    int chunkT = 8;
    for (int i = 0; i < 8; ++i) {
        size_t need = STATE_BYTES + (size_t)36864 * (size_t)cands[i];
        if (need <= ws_size) { chunkT = cands[i]; break; }
    }
    const int nchunks = TT / chunkT;

    _Float16* h1ring = (_Float16*)(wsp + STATE_BYTES);
    float* xpring = (float*)(wsp + STATE_BYTES + (size_t)2 * BB * chunkT * HH * 2);

    // zero persistent state (h/c/pooled); ws is re-poisoned before every call
    hipMemsetAsync(d_ws, 0, STATE_BYTES, stream);

    // pipeline: slot c runs A(c) || B(c-1) || C(c-2)
    const int nslots = nchunks + 2;
    for (int c = 0; c < nslots; ++c) {
        lstm_slot_kernel<<<66, 512, 0, stream>>>(
            x, Wih0, Whh0, bih0, bhh0, Wih1, Whh1, bih1, bhh1,
            h1s, c1s, h2s, c2s, pooled, h1ring, xpring,
            c, chunkT, nchunks);
    }
    head_kernel<<<BB, 128, 0, stream>>>(pooled, fcW1, fcb1, fcW2, fcb2, out);
}